// Round 2
// baseline (348.308 us; speedup 1.0000x reference)
//
#include <hip/hip_runtime.h>
#include <hip/hip_cooperative_groups.h>

namespace cg = cooperative_groups;

#define DF 128       // feature dim
#define CAP 16       // bucket capacity per node = one 64B cache line
#define GR 64        // GEMM rows per tile
#define PSLICES 256  // placement work-slices (tickets 0..PSLICES-1)

typedef __attribute__((ext_vector_type(8))) short short8;   // 8 bf16 (4 VGPRs)
typedef __attribute__((ext_vector_type(4))) float v4f;      // MFMA accumulator

__device__ __forceinline__ unsigned short f2bf(float x) {
    unsigned u = __float_as_uint(x);
    unsigned r = (u + 0x7FFFu + ((u >> 16) & 1u)) >> 16;    // RNE
    return (unsigned short)r;
}
__device__ __forceinline__ float bf2f(unsigned short h) {
    return __uint_as_float((unsigned)h << 16);
}
__device__ __forceinline__ unsigned pack2(float a, float b) {
    return (unsigned)f2bf(a) | ((unsigned)f2bf(b) << 16);
}

// ---------------------------------------------------------------------------
// prep: block 0 = index-dtype detect + header init; blocks 1..128 = W
// transpose to Bt[n][k] bf16; blocks 129.. = zero counts.
// hdr[0]=is32, hdr[1]=overflow counter, hdr[2]=phase-1 ticket counter.
// ---------------------------------------------------------------------------
__global__ __launch_bounds__(256) void prep_kernel(
    const int* __restrict__ idx32, int nE, int* __restrict__ hdr,
    const float* __restrict__ Wn, const float* __restrict__ Ws,
    unsigned short* __restrict__ Bt, int* __restrict__ counts, int cnt_ints)
{
    const int b = blockIdx.x;
    const int t = threadIdx.x;
    if (b == 0) {
        __shared__ int sh;
        if (t == 0) sh = 0;
        __syncthreads();
        int found = 0;
        for (int i = t; i < 2048 && i < nE; i += 256)
            if (idx32[2 * i + 1] != 0) found = 1;
        if (found) sh = 1;                 // benign race, any writer sets 1
        __syncthreads();
        if (t == 0) { hdr[0] = sh; hdr[1] = 0; hdr[2] = 0; }
    } else if (b <= 128) {
        int idx = (b - 1) * 256 + t;       // 0..32767 over [n][k]
        int n = idx >> 7, k = idx & 127;
        float v = (n < DF) ? Wn[(size_t)k * DF + n] : Ws[(size_t)k * DF + (n - DF)];
        Bt[idx] = f2bf(v);
    } else {
        int off = ((b - 129) * 256 + t) * 4;   // int index, int4 stores
        if (off < cnt_ints)
            *reinterpret_cast<int4*>(counts + off) = make_int4(0, 0, 0, 0);
    }
}

// ---------------------------------------------------------------------------
// placement slice T of PSLICES: pos = counts[dst]++; bucket or overflow list.
// ---------------------------------------------------------------------------
__device__ __forceinline__ void place_slice(
    int T, int t, const void* __restrict__ src, const void* __restrict__ dst,
    int nE, int* __restrict__ hdr, int* __restrict__ counts,
    int* __restrict__ buckets, int2* __restrict__ ovf)
{
    const int e0 = (int)((long long)T * nE / PSLICES);
    const int e1 = (int)((long long)(T + 1) * nE / PSLICES);
    const int is32 = hdr[0];
    if (is32) {
        const int* sp = (const int*)src;
        const int* dp = (const int*)dst;
        for (int e = e0 + t; e < e1; e += 256) {
            int s = sp[e], d = dp[e];
            int pos = atomicAdd(&counts[d], 1);
            if (pos < CAP) {
                buckets[(size_t)d * CAP + pos] = s;
            } else {
                int oi = atomicAdd(&hdr[1], 1);
                ovf[oi] = make_int2(s, d);
            }
        }
    } else {
        const long long* sp = (const long long*)src;
        const long long* dp = (const long long*)dst;
        for (int e = e0 + t; e < e1; e += 256) {
            int s = (int)sp[e], d = (int)dp[e];
            int pos = atomicAdd(&counts[d], 1);
            if (pos < CAP) {
                buckets[(size_t)d * CAP + pos] = s;
            } else {
                int oi = atomicAdd(&hdr[1], 1);
                ovf[oi] = make_int2(s, d);
            }
        }
    }
}

// ---------------------------------------------------------------------------
// GEMM tile: Y[r] = feat[r]@Wn -> Ybf (bf16); out[r] = feat[r]@Ws + bias.
// Caller guarantees a __syncthreads() separates successive calls.
// ---------------------------------------------------------------------------
__device__ __forceinline__ void gemm_tile(
    int tile, int t, const float* __restrict__ feat,
    const unsigned short* __restrict__ Bt, const float* __restrict__ bias,
    unsigned short* __restrict__ Ybf, float* __restrict__ out, int M,
    unsigned short (*As)[136], unsigned short (*Ys)[136])
{
    const int wave = t >> 6;
    const int lane = t & 63;
    const int nl   = lane & 15;
    const int quad = lane >> 4;
    const int block_row = tile * GR;

    // ---- stage A: flat lane-contiguous float4 loads, pack bf16 -> LDS ----
    {
        const float* base = feat + (size_t)block_row * DF;
#pragma unroll
        for (int it = 0; it < 8; it++) {
            const int idx = t * 4 + it * 1024;
            const int row = idx >> 7, col = idx & 127;
            float4 v;
            if (block_row + row < M)
                v = *reinterpret_cast<const float4*>(base + idx);
            else
                v = make_float4(0.f, 0.f, 0.f, 0.f);
            uint2 pk;
            pk.x = pack2(v.x, v.y);
            pk.y = pack2(v.z, v.w);
            *reinterpret_cast<uint2*>(&As[row][col]) = pk;
        }
    }

    // ---- preload B fragments (Bt is 64KB, L2-hot) ----
    const int n0 = wave * 64;
    short8 bfrag[4][4];
#pragma unroll
    for (int ct = 0; ct < 4; ct++)
#pragma unroll
        for (int kk = 0; kk < 4; kk++)
            bfrag[ct][kk] = *reinterpret_cast<const short8*>(
                Bt + (size_t)(n0 + ct * 16 + nl) * DF + kk * 32 + quad * 8);

    float bcol[4];
#pragma unroll
    for (int ct = 0; ct < 4; ct++) {
        int n = n0 + ct * 16 + nl;
        bcol[ct] = (n >= DF) ? bias[n - DF] : 0.f;
    }

    __syncthreads();

    // ---- compute: 4 row-tiles x 4 col-tiles x (K=128 as 4 mfma) ----
#pragma unroll
    for (int rt = 0; rt < 4; rt++) {
        short8 afrag[4];
#pragma unroll
        for (int kk = 0; kk < 4; kk++)
            afrag[kk] = *reinterpret_cast<const short8*>(
                &As[rt * 16 + nl][kk * 32 + quad * 8]);
#pragma unroll
        for (int ct = 0; ct < 4; ct++) {
            v4f acc = {0.f, 0.f, 0.f, 0.f};
#pragma unroll
            for (int kk = 0; kk < 4; kk++)
                acc = __builtin_amdgcn_mfma_f32_16x16x32_bf16(
                    afrag[kk], bfrag[ct][kk], acc, 0, 0, 0);
            const int n = n0 + ct * 16 + nl;
            const int lrow = rt * 16 + quad * 4;
            if (n < DF) {
#pragma unroll
                for (int r = 0; r < 4; r++)
                    Ys[lrow + r][n] = f2bf(acc[r]);
            } else {
#pragma unroll
                for (int r = 0; r < 4; r++) {
                    const int grow = block_row + lrow + r;
                    if (grow < M)
                        out[(size_t)grow * DF + (n - DF)] = acc[r] + bcol[ct];
                }
            }
        }
    }

    __syncthreads();

    // ---- coalesced Y writeback: 16B/lane uint4 stores ----
    {
        const int row = t >> 2;
        const int cb  = (t & 3) * 32;
        const int grow = block_row + row;
        if (grow < M) {
            const uint4* srcp = reinterpret_cast<const uint4*>(&Ys[row][cb]);
            uint4* dstp = reinterpret_cast<uint4*>(Ybf + (size_t)grow * DF + cb);
            dstp[0] = srcp[0];
            dstp[1] = srcp[1];
            dstp[2] = srcp[2];
            dstp[3] = srcp[3];
        }
    }
}

// ---------------------------------------------------------------------------
// gather: out[node] += sum of Y[s] over bucketed neighbors. 16 lanes/node,
// uint4/lane; load bursts pinned before accumulation via sched_barrier(0).
// ---------------------------------------------------------------------------
#define LDY(s) (*reinterpret_cast<const uint4*>(Ybf + (size_t)(s) * DF + lo))
#define ACC8(Y) do { \
        a0 += bf2f((unsigned short)((Y).x)); a1 += bf2f((unsigned short)((Y).x >> 16)); \
        a2 += bf2f((unsigned short)((Y).y)); a3 += bf2f((unsigned short)((Y).y >> 16)); \
        a4 += bf2f((unsigned short)((Y).z)); a5 += bf2f((unsigned short)((Y).z >> 16)); \
        a6 += bf2f((unsigned short)((Y).w)); a7 += bf2f((unsigned short)((Y).w >> 16)); \
    } while (0)

__device__ __forceinline__ void gather_all(
    int bid, int nblocks, int t,
    const unsigned short* __restrict__ Ybf, const int* __restrict__ counts,
    const int* __restrict__ buckets, const int* __restrict__ hdr,
    const int2* __restrict__ ovf, float* __restrict__ out, int M)
{
    const int lane = t & 15;
    const size_t lo = (size_t)lane * 8;
    const int chunks = (M * 16 + 255) / 256;

    for (int c = bid; c < chunks; c += nblocks) {
        const int grp = c * 16 + (t >> 4);
        if (grp >= M) continue;
        const int node = grp;
        const int deg_raw = counts[node];
        const int deg = min(deg_raw, CAP);
        const int* b = buckets + (size_t)node * CAP;
        float* op = out + (size_t)node * DF + lo;

        float a0 = 0.f, a1 = 0.f, a2 = 0.f, a3 = 0.f;
        float a4 = 0.f, a5 = 0.f, a6 = 0.f, a7 = 0.f;

        // batch 1: rows 0..7 + the out RMW read, all issued before any use
        int4 sa = *reinterpret_cast<const int4*>(b);
        int4 sb = *reinterpret_cast<const int4*>(b + 4);
        float4 o0 = *reinterpret_cast<const float4*>(op);
        float4 o1 = *reinterpret_cast<const float4*>(op + 4);
        uint4 y0, y1, y2, y3, y4, y5, y6, y7;
        if (0 < deg) y0 = LDY(sa.x);
        if (1 < deg) y1 = LDY(sa.y);
        if (2 < deg) y2 = LDY(sa.z);
        if (3 < deg) y3 = LDY(sa.w);
        if (4 < deg) y4 = LDY(sb.x);
        if (5 < deg) y5 = LDY(sb.y);
        if (6 < deg) y6 = LDY(sb.z);
        if (7 < deg) y7 = LDY(sb.w);
        __builtin_amdgcn_sched_barrier(0);
        if (0 < deg) ACC8(y0);
        if (1 < deg) ACC8(y1);
        if (2 < deg) ACC8(y2);
        if (3 < deg) ACC8(y3);
        if (4 < deg) ACC8(y4);
        if (5 < deg) ACC8(y5);
        if (6 < deg) ACC8(y6);
        if (7 < deg) ACC8(y7);

        // batch 2: rows 8..15 (P(deg>8) ~= 0.15)
        if (deg > 8) {
            int4 sc = *reinterpret_cast<const int4*>(b + 8);
            int4 sd = *reinterpret_cast<const int4*>(b + 12);
            uint4 z0, z1, z2, z3, z4, z5, z6, z7;
            if ( 8 < deg) z0 = LDY(sc.x);
            if ( 9 < deg) z1 = LDY(sc.y);
            if (10 < deg) z2 = LDY(sc.z);
            if (11 < deg) z3 = LDY(sc.w);
            if (12 < deg) z4 = LDY(sd.x);
            if (13 < deg) z5 = LDY(sd.y);
            if (14 < deg) z6 = LDY(sd.z);
            if (15 < deg) z7 = LDY(sd.w);
            __builtin_amdgcn_sched_barrier(0);
            if ( 8 < deg) ACC8(z0);
            if ( 9 < deg) ACC8(z1);
            if (10 < deg) ACC8(z2);
            if (11 < deg) ACC8(z3);
            if (12 < deg) ACC8(z4);
            if (13 < deg) ACC8(z5);
            if (14 < deg) ACC8(z6);
            if (15 < deg) ACC8(z7);
        }

        if (deg_raw <= CAP) {
            o0.x += a0; o0.y += a1; o0.z += a2; o0.w += a3;
            o1.x += a4; o1.y += a5; o1.z += a6; o1.w += a7;
            *reinterpret_cast<float4*>(op)     = o0;
            *reinterpret_cast<float4*>(op + 4) = o1;
        } else {
            unsafeAtomicAdd(op + 0, a0);
            unsafeAtomicAdd(op + 1, a1);
            unsafeAtomicAdd(op + 2, a2);
            unsafeAtomicAdd(op + 3, a3);
            unsafeAtomicAdd(op + 4, a4);
            unsafeAtomicAdd(op + 5, a5);
            unsafeAtomicAdd(op + 6, a6);
            unsafeAtomicAdd(op + 7, a7);
        }
    }

    // ---- overflow edges, grid-stride over 16-lane groups ----
    const int n_ovf = hdr[1];
    const int gstride = nblocks * 16;
    for (int i = bid * 16 + (t >> 4); i < n_ovf; i += gstride) {
        int2 sd = ovf[i];
        uint4 y = LDY(sd.x);
        float* p = out + (size_t)sd.y * DF + lo;
        unsafeAtomicAdd(p + 0, bf2f((unsigned short)(y.x)));
        unsafeAtomicAdd(p + 1, bf2f((unsigned short)(y.x >> 16)));
        unsafeAtomicAdd(p + 2, bf2f((unsigned short)(y.y)));
        unsafeAtomicAdd(p + 3, bf2f((unsigned short)(y.y >> 16)));
        unsafeAtomicAdd(p + 4, bf2f((unsigned short)(y.z)));
        unsafeAtomicAdd(p + 5, bf2f((unsigned short)(y.z >> 16)));
        unsafeAtomicAdd(p + 6, bf2f((unsigned short)(y.w)));
        unsafeAtomicAdd(p + 7, bf2f((unsigned short)(y.w >> 16)));
    }
}
#undef LDY
#undef ACC8

// ---------------------------------------------------------------------------
// coop: phase 1 = ticket queue over {placement slices, GEMM tiles};
// grid.sync(); phase 2 = gather. One launch, no inter-kernel boundary.
// __launch_bounds__(256,4) caps VGPR<=128 so 4 blocks/CU (LDS also gives 4).
// ---------------------------------------------------------------------------
__global__ __launch_bounds__(256, 4) void coop_kernel(
    const float* __restrict__ feat, const unsigned short* __restrict__ Bt,
    const float* __restrict__ bias, unsigned short* __restrict__ Ybf,
    float* __restrict__ out, int M,
    const void* __restrict__ src, const void* __restrict__ dst, int nE,
    int* __restrict__ hdr, int* __restrict__ counts, int* __restrict__ buckets,
    int2* __restrict__ ovf, int ntiles)
{
    __shared__ unsigned short As[GR][136];
    __shared__ unsigned short Ys[GR][136];
    __shared__ int sh_t;
    const int t = threadIdx.x;
    const int NT = PSLICES + ntiles;

    for (;;) {
        __syncthreads();
        if (t == 0) sh_t = atomicAdd(&hdr[2], 1);
        __syncthreads();
        const int T = sh_t;
        if (T >= NT) break;
        if (T < PSLICES)
            place_slice(T, t, src, dst, nE, hdr, counts, buckets, ovf);
        else
            gemm_tile(T - PSLICES, t, feat, Bt, bias, Ybf, out, M, As, Ys);
    }

    cg::this_grid().sync();

    gather_all((int)blockIdx.x, (int)gridDim.x, t,
               Ybf, counts, buckets, hdr, ovf, out, M);
}

// ---------------------------------------------------------------------------
// fallback path (round-0 structure) if cooperative launch is unavailable
// ---------------------------------------------------------------------------
__global__ __launch_bounds__(256) void fb_fused_kernel(
    const float* __restrict__ feat, const unsigned short* __restrict__ Bt,
    const float* __restrict__ bias, unsigned short* __restrict__ Ybf,
    float* __restrict__ out, int M,
    const void* __restrict__ src, const void* __restrict__ dst, int nE,
    int* __restrict__ hdr, int* __restrict__ counts, int* __restrict__ buckets,
    int2* __restrict__ ovf)
{
    __shared__ unsigned short As[GR][136];
    __shared__ unsigned short Ys[GR][136];
    const int t = threadIdx.x;
    if (blockIdx.x < PSLICES)
        place_slice(blockIdx.x, t, src, dst, nE, hdr, counts, buckets, ovf);
    else
        gemm_tile(blockIdx.x - PSLICES, t, feat, Bt, bias, Ybf, out, M, As, Ys);
}

__global__ __launch_bounds__(256) void fb_gather_kernel(
    const unsigned short* __restrict__ Ybf, const int* __restrict__ counts,
    const int* __restrict__ buckets, const int* __restrict__ hdr,
    const int2* __restrict__ ovf, float* __restrict__ out, int M)
{
    gather_all((int)blockIdx.x, (int)gridDim.x, (int)threadIdx.x,
               Ybf, counts, buckets, hdr, ovf, out, M);
}

extern "C" void kernel_launch(void* const* d_in, const int* in_sizes, int n_in,
                              void* d_out, int out_size, void* d_ws, size_t ws_size,
                              hipStream_t stream) {
    const float* feat = (const float*)d_in[0];
    const void*  src  = d_in[1];
    const void*  dst  = d_in[2];
    const float* Wn   = (const float*)d_in[3];
    const float* bias = (const float*)d_in[4];
    const float* Wsf  = (const float*)d_in[5];
    float* out = (float*)d_out;

    int M  = in_sizes[0] / DF;   // 100000
    int nE = in_sizes[1];        // 600000

    // workspace: [hdr 256B][counts][buckets][Bt 64KB][Ybf][ovf]
    const size_t cnt_off   = 256;
    const size_t cnt_bytes = (((size_t)(M + 1) * 4) + 255) & ~(size_t)255;
    const size_t bkt_off   = cnt_off + cnt_bytes;
    const size_t bkt_bytes = (size_t)M * CAP * sizeof(int);
    const size_t bt_off    = (bkt_off + bkt_bytes + 255) & ~(size_t)255;
    const size_t bt_bytes  = (size_t)256 * DF * sizeof(unsigned short);
    const size_t y_off     = bt_off + bt_bytes;
    const size_t y_bytes   = (size_t)M * DF * sizeof(unsigned short);
    const size_t ovf_off   = (y_off + y_bytes + 255) & ~(size_t)255;

    int*            hdr     = (int*)d_ws;
    int*            counts  = (int*)((char*)d_ws + cnt_off);
    int*            buckets = (int*)((char*)d_ws + bkt_off);
    unsigned short* Bt      = (unsigned short*)((char*)d_ws + bt_off);
    unsigned short* Ybf     = (unsigned short*)((char*)d_ws + y_off);
    int2*           ovf     = (int2*)((char*)d_ws + ovf_off);

    const int cnt_ints = (int)(cnt_bytes / 4);
    const int nzb = (cnt_ints + 1023) / 1024;
    prep_kernel<<<1 + 128 + nzb, 256, 0, stream>>>(
        (const int*)src, nE, hdr, Wn, Wsf, Bt, counts, cnt_ints);

    int ntiles = (M + GR - 1) / GR;

    static int s_mode = 0;        // 0 unknown, 1 coop, -1 fallback
    static int s_nblocks = 1024;
    if (s_mode == 0) {
        int occ = 0;
        hipError_t e1 = hipOccupancyMaxActiveBlocksPerMultiprocessor(
            &occ, coop_kernel, 256, 0);
        int ncu = 256;
        hipDeviceProp_t prop;
        int dev = 0;
        if (hipGetDevice(&dev) == hipSuccess &&
            hipGetDeviceProperties(&prop, dev) == hipSuccess)
            ncu = prop.multiProcessorCount;
        if (e1 == hipSuccess && occ > 0) {
            s_nblocks = occ * ncu;
            s_mode = 1;
        } else {
            s_mode = -1;
        }
    }

    if (s_mode == 1) {
        void* args[] = {
            (void*)&feat, (void*)&Bt, (void*)&bias, (void*)&Ybf, (void*)&out,
            (void*)&M, (void*)&src, (void*)&dst, (void*)&nE,
            (void*)&hdr, (void*)&counts, (void*)&buckets, (void*)&ovf,
            (void*)&ntiles };
        hipError_t e = hipLaunchCooperativeKernel(
            (const void*)coop_kernel, dim3(s_nblocks), dim3(256),
            args, 0, stream);
        if (e != hipSuccess) s_mode = -1;   // fall through to 2-kernel path
    }

    if (s_mode == -1) {
        fb_fused_kernel<<<PSLICES + ntiles, 256, 0, stream>>>(
            feat, Bt, bias, Ybf, out, M, src, dst, nE,
            hdr, counts, buckets, ovf);
        const int gablocks = (int)(((long long)M * 16 + 255) / 256);
        fb_gather_kernel<<<gablocks, 256, 0, stream>>>(
            Ybf, counts, buckets, hdr, ovf, out, M);
    }
}

// Round 3
// 193.920 us; speedup vs baseline: 1.7961x; 1.7961x over previous
//
#include <hip/hip_runtime.h>

#define DF 128     // feature dim
#define CAP 16     // bucket capacity per node = one 64B cache line
#define GR 64      // GEMM rows per block
#define PBLK 256   // placement blocks (block-specialized, run concurrently w/ GEMM)

typedef __attribute__((ext_vector_type(8))) short short8;   // 8 bf16 (4 VGPRs)
typedef __attribute__((ext_vector_type(4))) float v4f;      // MFMA accumulator

__device__ __forceinline__ unsigned short f2bf(float x) {
    unsigned u = __float_as_uint(x);
    unsigned r = (u + 0x7FFFu + ((u >> 16) & 1u)) >> 16;    // RNE
    return (unsigned short)r;
}
__device__ __forceinline__ float bf2f(unsigned short h) {
    return __uint_as_float((unsigned)h << 16);
}
__device__ __forceinline__ unsigned pack2(float a, float b) {
    return (unsigned)f2bf(a) | ((unsigned)f2bf(b) << 16);
}

// ---------------------------------------------------------------------------
// prep: block 0 = index-dtype detect + header init + zero sentinel row
// Ybf[M]; blocks 1..128 = W transpose to Bt[n][k] bf16; blocks 129.. = zero
// counts. hdr[0] = 1 if indices are int32, else 0 (int64). hdr[1] = overflow.
// ---------------------------------------------------------------------------
__global__ __launch_bounds__(256) void prep_kernel(
    const int* __restrict__ idx32, int nE, int* __restrict__ hdr,
    const float* __restrict__ Wn, const float* __restrict__ Ws,
    unsigned short* __restrict__ Bt, int* __restrict__ counts, int cnt_ints,
    unsigned short* __restrict__ Ybf, int M)
{
    const int b = blockIdx.x;
    const int t = threadIdx.x;
    if (b == 0) {
        __shared__ int sh;
        if (t == 0) sh = 0;
        __syncthreads();
        int found = 0;
        for (int i = t; i < 2048 && i < nE; i += 256)
            if (idx32[2 * i + 1] != 0) found = 1;
        if (found) sh = 1;                 // benign race, any writer sets 1
        __syncthreads();
        if (t == 0) { hdr[0] = sh; hdr[1] = 0; }
        // zero sentinel row Ybf[M] (256B = 64 uints)
        if (t < 64)
            reinterpret_cast<unsigned*>(Ybf + (size_t)M * DF)[t] = 0u;
    } else if (b <= 128) {
        int idx = (b - 1) * 256 + t;       // 0..32767 over [n][k]
        int n = idx >> 7, k = idx & 127;
        float v = (n < DF) ? Wn[(size_t)k * DF + n] : Ws[(size_t)k * DF + (n - DF)];
        Bt[idx] = f2bf(v);
    } else {
        int off = ((b - 129) * 256 + t) * 4;   // int index, int4 stores
        if (off < cnt_ints)
            *reinterpret_cast<int4*>(counts + off) = make_int4(0, 0, 0, 0);
    }
}

// ---------------------------------------------------------------------------
// fused: blocks [0,PBLK) = edge placement (grid-stride); blocks [PBLK, ...)
// = GEMM tiles. Disjoint data -> true concurrent execution across CUs.
//   GEMM tile: Y[r] = feat[r]@Wn -> Ybf (bf16); out[r] = feat[r]@Ws + bias.
//   Placement: pos = counts[dst]++; bucket or overflow list.
// ---------------------------------------------------------------------------
__global__ __launch_bounds__(256) void fused_kernel(
    const float* __restrict__ feat, const unsigned short* __restrict__ Bt,
    const float* __restrict__ bias, unsigned short* __restrict__ Ybf,
    float* __restrict__ out, int M,
    const void* __restrict__ src, const void* __restrict__ dst, int nE,
    int* __restrict__ hdr, int* __restrict__ counts, int* __restrict__ buckets,
    int2* __restrict__ ovf)
{
    const int t = threadIdx.x;

    if (blockIdx.x < PBLK) {
        // ---------------- placement blocks ----------------
        const int is32 = hdr[0];
        const int stride = PBLK * 256;
        if (is32) {
            const int* sp = (const int*)src;
            const int* dp = (const int*)dst;
            for (int e = blockIdx.x * 256 + t; e < nE; e += stride) {
                int s = sp[e], d = dp[e];
                int pos = atomicAdd(&counts[d], 1);
                if (pos < CAP) {
                    buckets[(size_t)d * CAP + pos] = s;
                } else {
                    int oi = atomicAdd(&hdr[1], 1);
                    ovf[oi] = make_int2(s, d);
                }
            }
        } else {
            const long long* sp = (const long long*)src;
            const long long* dp = (const long long*)dst;
            for (int e = blockIdx.x * 256 + t; e < nE; e += stride) {
                int s = (int)sp[e], d = (int)dp[e];
                int pos = atomicAdd(&counts[d], 1);
                if (pos < CAP) {
                    buckets[(size_t)d * CAP + pos] = s;
                } else {
                    int oi = atomicAdd(&hdr[1], 1);
                    ovf[oi] = make_int2(s, d);
                }
            }
        }
        return;
    }

    // ---------------- GEMM blocks ----------------
    __shared__ unsigned short As[GR][136];   // A tile bf16
    __shared__ unsigned short Ys[GR][136];   // Y staging bf16

    const int wave = t >> 6;
    const int lane = t & 63;
    const int nl   = lane & 15;
    const int quad = lane >> 4;
    const int block_row = (blockIdx.x - PBLK) * GR;

    // ---- stage A: flat lane-contiguous float4 loads, pack bf16 -> LDS ----
    {
        const float* base = feat + (size_t)block_row * DF;
#pragma unroll
        for (int it = 0; it < 8; it++) {
            const int idx = t * 4 + it * 1024;
            const int row = idx >> 7, col = idx & 127;
            float4 v;
            if (block_row + row < M)
                v = *reinterpret_cast<const float4*>(base + idx);
            else
                v = make_float4(0.f, 0.f, 0.f, 0.f);
            uint2 pk;
            pk.x = pack2(v.x, v.y);
            pk.y = pack2(v.z, v.w);
            *reinterpret_cast<uint2*>(&As[row][col]) = pk;
        }
    }

    // ---- preload B fragments (Bt is 64KB, L2-hot) ----
    const int n0 = wave * 64;
    short8 bfrag[4][4];
#pragma unroll
    for (int ct = 0; ct < 4; ct++)
#pragma unroll
        for (int kk = 0; kk < 4; kk++)
            bfrag[ct][kk] = *reinterpret_cast<const short8*>(
                Bt + (size_t)(n0 + ct * 16 + nl) * DF + kk * 32 + quad * 8);

    float bcol[4];
#pragma unroll
    for (int ct = 0; ct < 4; ct++) {
        int n = n0 + ct * 16 + nl;
        bcol[ct] = (n >= DF) ? bias[n - DF] : 0.f;
    }

    __syncthreads();

    // ---- compute: 4 row-tiles x 4 col-tiles x (K=128 as 4 mfma) ----
#pragma unroll
    for (int rt = 0; rt < 4; rt++) {
        short8 afrag[4];
#pragma unroll
        for (int kk = 0; kk < 4; kk++)
            afrag[kk] = *reinterpret_cast<const short8*>(
                &As[rt * 16 + nl][kk * 32 + quad * 8]);
#pragma unroll
        for (int ct = 0; ct < 4; ct++) {
            v4f acc = {0.f, 0.f, 0.f, 0.f};
#pragma unroll
            for (int kk = 0; kk < 4; kk++)
                acc = __builtin_amdgcn_mfma_f32_16x16x32_bf16(
                    afrag[kk], bfrag[ct][kk], acc, 0, 0, 0);
            const int n = n0 + ct * 16 + nl;
            const int lrow = rt * 16 + quad * 4;
            if (n < DF) {
#pragma unroll
                for (int r = 0; r < 4; r++)
                    Ys[lrow + r][n] = f2bf(acc[r]);
            } else {
#pragma unroll
                for (int r = 0; r < 4; r++) {
                    const int grow = block_row + lrow + r;
                    if (grow < M)
                        out[(size_t)grow * DF + (n - DF)] = acc[r] + bcol[ct];
                }
            }
        }
    }

    __syncthreads();

    // ---- coalesced Y writeback: 16B/lane uint4 stores ----
    {
        const int row = t >> 2;
        const int cb  = (t & 3) * 32;
        const int grow = block_row + row;
        if (grow < M) {
            const uint4* srcp = reinterpret_cast<const uint4*>(&Ys[row][cb]);
            uint4* dstp = reinterpret_cast<uint4*>(Ybf + (size_t)grow * DF + cb);
            dstp[0] = srcp[0];
            dstp[1] = srcp[1];
            dstp[2] = srcp[2];
            dstp[3] = srcp[3];
        }
    }
}

// ---------------------------------------------------------------------------
// gather: out[node] += sum over bucketed neighbors of Y[s] (bf16 rows).
// 16 lanes/node, uint4/lane. BRANCH-FREE burst: indices for slots >= deg are
// cndmask-selected to the zero sentinel row M, so all 8 row loads (plus the
// out RMW read) issue unconditionally and stay clustered (sched_barrier).
// ---------------------------------------------------------------------------
__global__ __launch_bounds__(256) void gather_kernel(
    const unsigned short* __restrict__ Ybf,
    const int* __restrict__ counts, const int* __restrict__ buckets,
    const int* __restrict__ hdr, const int2* __restrict__ ovf,
    float* __restrict__ out, int M, int ngroups)
{
    const int gid  = blockIdx.x * 256 + threadIdx.x;
    const int grp  = gid >> 4;
    const int lane = gid & 15;
    const size_t lo = (size_t)lane * 8;

#define LDY(s) (*reinterpret_cast<const uint4*>(Ybf + (size_t)(s) * DF + lo))
#define ACC8(Y) do { \
        a0 += bf2f((unsigned short)((Y).x)); a1 += bf2f((unsigned short)((Y).x >> 16)); \
        a2 += bf2f((unsigned short)((Y).y)); a3 += bf2f((unsigned short)((Y).y >> 16)); \
        a4 += bf2f((unsigned short)((Y).z)); a5 += bf2f((unsigned short)((Y).z >> 16)); \
        a6 += bf2f((unsigned short)((Y).w)); a7 += bf2f((unsigned short)((Y).w >> 16)); \
    } while (0)

    if (grp < M) {
        const int node = grp;
        const int deg_raw = counts[node];
        const int deg = min(deg_raw, CAP);
        const int* b = buckets + (size_t)node * CAP;
        float* op = out + (size_t)node * DF + lo;

        float a0 = 0.f, a1 = 0.f, a2 = 0.f, a3 = 0.f;
        float a4 = 0.f, a5 = 0.f, a6 = 0.f, a7 = 0.f;

        // slot indices 0..7, sentinel-selected (v_cndmask, no branches)
        int4 sa = *reinterpret_cast<const int4*>(b);
        int4 sb = *reinterpret_cast<const int4*>(b + 4);
        const int i0 = (0 < deg) ? sa.x : M;
        const int i1 = (1 < deg) ? sa.y : M;
        const int i2 = (2 < deg) ? sa.z : M;
        const int i3 = (3 < deg) ? sa.w : M;
        const int i4 = (4 < deg) ? sb.x : M;
        const int i5 = (5 < deg) ? sb.y : M;
        const int i6 = (6 < deg) ? sb.z : M;
        const int i7 = (7 < deg) ? sb.w : M;

        // burst: 8 row loads + out RMW read, all in flight together
        uint4 y0 = LDY(i0);
        uint4 y1 = LDY(i1);
        uint4 y2 = LDY(i2);
        uint4 y3 = LDY(i3);
        uint4 y4 = LDY(i4);
        uint4 y5 = LDY(i5);
        uint4 y6 = LDY(i6);
        uint4 y7 = LDY(i7);
        float4 o0 = *reinterpret_cast<const float4*>(op);
        float4 o1 = *reinterpret_cast<const float4*>(op + 4);
        __builtin_amdgcn_sched_barrier(0);
        ACC8(y0); ACC8(y1); ACC8(y2); ACC8(y3);
        ACC8(y4); ACC8(y5); ACC8(y6); ACC8(y7);

        // slots 8..15 (P(deg>8) ~= 0.15): same branch-free burst
        if (deg > 8) {
            int4 sc = *reinterpret_cast<const int4*>(b + 8);
            int4 sd = *reinterpret_cast<const int4*>(b + 12);
            const int j0 = ( 8 < deg) ? sc.x : M;
            const int j1 = ( 9 < deg) ? sc.y : M;
            const int j2 = (10 < deg) ? sc.z : M;
            const int j3 = (11 < deg) ? sc.w : M;
            const int j4 = (12 < deg) ? sd.x : M;
            const int j5 = (13 < deg) ? sd.y : M;
            const int j6 = (14 < deg) ? sd.z : M;
            const int j7 = (15 < deg) ? sd.w : M;
            uint4 z0 = LDY(j0);
            uint4 z1 = LDY(j1);
            uint4 z2 = LDY(j2);
            uint4 z3 = LDY(j3);
            uint4 z4 = LDY(j4);
            uint4 z5 = LDY(j5);
            uint4 z6 = LDY(j6);
            uint4 z7 = LDY(j7);
            __builtin_amdgcn_sched_barrier(0);
            ACC8(z0); ACC8(z1); ACC8(z2); ACC8(z3);
            ACC8(z4); ACC8(z5); ACC8(z6); ACC8(z7);
        }

        if (deg_raw <= CAP) {
            o0.x += a0; o0.y += a1; o0.z += a2; o0.w += a3;
            o1.x += a4; o1.y += a5; o1.z += a6; o1.w += a7;
            *reinterpret_cast<float4*>(op)     = o0;
            *reinterpret_cast<float4*>(op + 4) = o1;
        } else {
            unsafeAtomicAdd(op + 0, a0);
            unsafeAtomicAdd(op + 1, a1);
            unsafeAtomicAdd(op + 2, a2);
            unsafeAtomicAdd(op + 3, a3);
            unsafeAtomicAdd(op + 4, a4);
            unsafeAtomicAdd(op + 5, a5);
            unsafeAtomicAdd(op + 6, a6);
            unsafeAtomicAdd(op + 7, a7);
        }
    }

    // ---- overflow edges, grid-stride over 16-lane groups ----
    int n_ovf = hdr[1];
    for (int i = grp; i < n_ovf; i += ngroups) {
        int2 sd = ovf[i];
        uint4 y = LDY(sd.x);
        float* p = out + (size_t)sd.y * DF + lo;
        unsafeAtomicAdd(p + 0, bf2f((unsigned short)(y.x)));
        unsafeAtomicAdd(p + 1, bf2f((unsigned short)(y.x >> 16)));
        unsafeAtomicAdd(p + 2, bf2f((unsigned short)(y.y)));
        unsafeAtomicAdd(p + 3, bf2f((unsigned short)(y.y >> 16)));
        unsafeAtomicAdd(p + 4, bf2f((unsigned short)(y.z)));
        unsafeAtomicAdd(p + 5, bf2f((unsigned short)(y.z >> 16)));
        unsafeAtomicAdd(p + 6, bf2f((unsigned short)(y.w)));
        unsafeAtomicAdd(p + 7, bf2f((unsigned short)(y.w >> 16)));
    }
#undef LDY
#undef ACC8
}

extern "C" void kernel_launch(void* const* d_in, const int* in_sizes, int n_in,
                              void* d_out, int out_size, void* d_ws, size_t ws_size,
                              hipStream_t stream) {
    const float* feat = (const float*)d_in[0];
    const void*  src  = d_in[1];
    const void*  dst  = d_in[2];
    const float* Wn   = (const float*)d_in[3];
    const float* bias = (const float*)d_in[4];
    const float* Wsf  = (const float*)d_in[5];
    float* out = (float*)d_out;

    const int M  = in_sizes[0] / DF;   // 100000
    const int nE = in_sizes[1];        // 600000

    // workspace: [hdr 256B][counts][buckets][Bt 64KB][Ybf (M+1 rows)][ovf]
    const size_t cnt_off   = 256;
    const size_t cnt_bytes = (((size_t)(M + 1) * 4) + 255) & ~(size_t)255;
    const size_t bkt_off   = cnt_off + cnt_bytes;
    const size_t bkt_bytes = (size_t)M * CAP * sizeof(int);
    const size_t bt_off    = (bkt_off + bkt_bytes + 255) & ~(size_t)255;
    const size_t bt_bytes  = (size_t)256 * DF * sizeof(unsigned short);
    const size_t y_off     = bt_off + bt_bytes;
    const size_t y_bytes   = (size_t)(M + 1) * DF * sizeof(unsigned short);
    const size_t ovf_off   = (y_off + y_bytes + 255) & ~(size_t)255;

    int*            hdr     = (int*)d_ws;
    int*            counts  = (int*)((char*)d_ws + cnt_off);
    int*            buckets = (int*)((char*)d_ws + bkt_off);
    unsigned short* Bt      = (unsigned short*)((char*)d_ws + bt_off);
    unsigned short* Ybf     = (unsigned short*)((char*)d_ws + y_off);
    int2*           ovf     = (int2*)((char*)d_ws + ovf_off);

    const int cnt_ints = (int)(cnt_bytes / 4);
    const int nzb = (cnt_ints + 1023) / 1024;
    prep_kernel<<<1 + 128 + nzb, 256, 0, stream>>>(
        (const int*)src, nE, hdr, Wn, Wsf, Bt, counts, cnt_ints, Ybf, M);

    const int gemm_blocks = (M + GR - 1) / GR;
    fused_kernel<<<PBLK + gemm_blocks, 256, 0, stream>>>(
        feat, Bt, bias, Ybf, out, M, src, dst, nE,
        hdr, counts, buckets, ovf);

    const int gablocks = (int)(((long long)M * 16 + 255) / 256);
    const int ngroups = gablocks * 16;
    gather_kernel<<<gablocks, 256, 0, stream>>>(
        Ybf, counts, buckets, hdr, ovf, out, M, ngroups);
}